// Round 5
// baseline (305.720 us; speedup 1.0000x reference)
//
#include <hip/hip_runtime.h>
#include <hip/hip_bf16.h>
#include <stdint.h>

// ---------------------------------------------------------------------------
// JointEmbeddingClassifier on MI355X (gfx950) — R5.
// R4 post-mortem: gemm1 BK=128 hit 905 TF = the m97-structure plateau
// (MfmaUtil 38%, conflicts 0). R5 attacks the residual kernel time:
//   (1) k_prep: 4625 fat blocks instead of 14465 tiny ones
//   (2) k_head: BK=128 -> 8 serial K-iterations instead of 16 (head is
//       latency-bound: only ~64 working blocks, <=1 per CU)
// gemm1 unchanged. If total stays >=295us, the ~175us non-kernel gap is
// harness-fixed and we are at the controllable roofline.
// ---------------------------------------------------------------------------

typedef __attribute__((ext_vector_type(4))) float  floatx4;
typedef __attribute__((ext_vector_type(8))) short  shortx8;
typedef __attribute__((ext_vector_type(4))) short  shortx4;
typedef __attribute__((ext_vector_type(8))) __bf16 bf16x8;

static __device__ __forceinline__ ushort f32_to_bf16_rne(float f) {
  uint32_t u = __builtin_bit_cast(uint32_t, f);
  u += 0x7FFFu + ((u >> 16) & 1u);      // RNE (no NaN inputs here)
  return (ushort)(u >> 16);
}

// async global->LDS, 16B per lane. LDS dest = wave-uniform base + lane*16;
// global address may be fully per-lane (used for perm-indirected rows).
static __device__ __forceinline__ void async_copy16(const void* g, void* lds) {
  __builtin_amdgcn_global_load_lds(
      (__attribute__((address_space(1))) void*)(uintptr_t)g,
      (__attribute__((address_space(3))) void*)(uintptr_t)lds,
      16, 0, 0);
}

// ======================= fused prep (one launch, fat blocks) ===============
// blocks [0,2047]    : cast x f32->bf16 (32 els/thread)
// blocks [2048,4095] : transpose Wp|Ws -> Bt1 bf16 [2048][4096] (64x64 tile)
// blocks [4096,4623] : pack cwb [32][128][1024] + Wcb [128][1024] (8 rows/blk)
// block  [4624]      : counting sort of y -> perm, offs
__global__ __launch_bounds__(256) void k_prep(
    const float* __restrict__ x,   const int* __restrict__ y,
    const float* __restrict__ Wp,  const float* __restrict__ Ws,
    const float* __restrict__ Wc,
    const float* __restrict__ cw0, const float* __restrict__ cw1,
    ushort* __restrict__ xb,  ushort* __restrict__ Bt1,
    ushort* __restrict__ cwb, ushort* __restrict__ Wcb,
    int* __restrict__ perm, int* __restrict__ offs)
{
  __shared__ __align__(16) ushort tile[64 * 72];
  __shared__ int hist[32], hbase[32], hcur[32];
  const int b = blockIdx.x;
  const int t = threadIdx.x;

  if (b < 2048) {
    // ---- cast x -> bf16: block covers 8192 contiguous elements ----
    const size_t base = (size_t)b * 8192 + t * 8;
    #pragma unroll
    for (int it = 0; it < 4; ++it) {
      const size_t i = base + it * 2048;
      floatx4 a = *reinterpret_cast<const floatx4*>(x + i);
      floatx4 c = *reinterpret_cast<const floatx4*>(x + i + 4);
      shortx8 o;
      o[0] = (short)f32_to_bf16_rne(a[0]); o[1] = (short)f32_to_bf16_rne(a[1]);
      o[2] = (short)f32_to_bf16_rne(a[2]); o[3] = (short)f32_to_bf16_rne(a[3]);
      o[4] = (short)f32_to_bf16_rne(c[0]); o[5] = (short)f32_to_bf16_rne(c[1]);
      o[6] = (short)f32_to_bf16_rne(c[2]); o[7] = (short)f32_to_bf16_rne(c[3]);
      *reinterpret_cast<shortx8*>(xb + i) = o;
    }
  } else if (b < 4096) {
    // ---- transpose one 64x64 tile of Wp|Ws into Bt1 (K-contiguous) ----
    const int vt = b - 2048;             // 0..2047
    const int z = vt >> 10, rest = vt & 1023;
    const int nt = rest >> 6, kt = rest & 63;
    const float* W = z ? Ws : Wp;
    const int r = t >> 4, c = (t & 15) * 4;
    #pragma unroll
    for (int j = 0; j < 4; ++j) {
      const int kk = r + j * 16;
      floatx4 v = *reinterpret_cast<const floatx4*>(
          W + (size_t)(kt * 64 + kk) * 1024 + nt * 64 + c);
      tile[(c + 0) * 72 + kk] = f32_to_bf16_rne(v[0]);
      tile[(c + 1) * 72 + kk] = f32_to_bf16_rne(v[1]);
      tile[(c + 2) * 72 + kk] = f32_to_bf16_rne(v[2]);
      tile[(c + 3) * 72 + kk] = f32_to_bf16_rne(v[3]);
    }
    __syncthreads();
    const int nl = t >> 3, ch = t & 7;
    #pragma unroll
    for (int j = 0; j < 2; ++j) {
      const int n = nl + j * 32;
      shortx8 v = *reinterpret_cast<const shortx8*>(tile + n * 72 + ch * 8);
      *reinterpret_cast<shortx8*>(
          Bt1 + (size_t)(z * 1024 + nt * 64 + n) * 4096 + kt * 64 + ch * 8) = v;
    }
  } else if (b < 4624) {
    // ---- pack cwb (rows: 32 cw0 | 64 cw1 | 32 zero per class) + Wcb ----
    const int k = t * 4;
    #pragma unroll 1
    for (int j = 0; j < 8; ++j) {
      const int row = (b - 4096) * 8 + j;        // 0..4223
      float v0 = 0.f, v1 = 0.f, v2 = 0.f, v3 = 0.f;
      ushort* dst;
      if (row < 4096) {
        const int c = row >> 7, n = row & 127;
        if (n < 32) {
          floatx4 f = *reinterpret_cast<const floatx4*>(cw0 + (size_t)(c * 32 + n) * 1024 + k);
          v0 = f[0]; v1 = f[1]; v2 = f[2]; v3 = f[3];
        } else if (n < 96) {
          floatx4 f = *reinterpret_cast<const floatx4*>(cw1 + (size_t)(c * 64 + (n - 32)) * 1024 + k);
          v0 = f[0]; v1 = f[1]; v2 = f[2]; v3 = f[3];
        }
        dst = cwb + (size_t)row * 1024 + k;
      } else {
        const int n = row - 4096;                // 0..127
        if (n < 32) {
          v0 = Wc[(k + 0) * 32 + n]; v1 = Wc[(k + 1) * 32 + n];
          v2 = Wc[(k + 2) * 32 + n]; v3 = Wc[(k + 3) * 32 + n];
        }
        dst = Wcb + (size_t)n * 1024 + k;
      }
      shortx4 o;
      o[0] = (short)f32_to_bf16_rne(v0); o[1] = (short)f32_to_bf16_rne(v1);
      o[2] = (short)f32_to_bf16_rne(v2); o[3] = (short)f32_to_bf16_rne(v3);
      *reinterpret_cast<shortx4*>(dst) = o;
    }
  } else {
    // ---- bucket: counting sort by class (intra-class order irrelevant) ----
    if (t < 32) { hist[t] = 0; hcur[t] = 0; }
    __syncthreads();
    int yv[16];
    #pragma unroll
    for (int i = 0; i < 16; ++i) { yv[i] = y[t * 16 + i]; atomicAdd(&hist[yv[i]], 1); }
    __syncthreads();
    if (t == 0) {
      int s = 0;
      for (int c = 0; c < 32; ++c) { hbase[c] = s; offs[c] = s; s += hist[c]; }
      offs[32] = s;
    }
    __syncthreads();
    #pragma unroll
    for (int i = 0; i < 16; ++i) {
      const int c = yv[i];
      const int p = atomicAdd(&hcur[c], 1);
      perm[hbase[c] + p] = t * 16 + i;
    }
  }
}

// ======================= gemm1: BK=128 (unchanged from R4) =================
// C[4096,2048] = xb . Bt1^T ; cols 0..1023 -> P (+bp), 1024..2047 -> S (+bs).
// LDS 2x32KB, physical 16B-chunk = logical ^ (row&15) swizzle.
__global__ __launch_bounds__(256) void k_gemm1(
    const ushort* __restrict__ xb, const ushort* __restrict__ Bt1,
    const float* __restrict__ bp, const float* __restrict__ bs,
    float* __restrict__ outP, float* __restrict__ outS,
    ushort* __restrict__ Pb, ushort* __restrict__ Sb)
{
  __shared__ __align__(16) ushort lA[128 * 128];   // 32 KB
  __shared__ __align__(16) ushort lB[128 * 128];   // 32 KB
  floatx4 acc[4][4];
  const floatx4 z4 = {0.f, 0.f, 0.f, 0.f};
  #pragma unroll
  for (int i = 0; i < 4; ++i)
    #pragma unroll
    for (int j = 0; j < 4; ++j) acc[i][j] = z4;

  const int t    = threadIdx.x;
  const int w    = t >> 6;
  const int lane = t & 63;
  const int wr   = w >> 1;
  const int wc   = w & 1;
  const int r16  = lane & 15;
  const int quad = lane >> 4;
  const int sr4  = lane >> 4;   // staging: row within 4-row group
  const int sc16 = lane & 15;   // staging: 16B chunk slot (16 per 256B row)

  const ushort* Abase = xb  + (size_t)(blockIdx.x * 128) * 4096;
  const ushort* Bbase = Bt1 + (size_t)(blockIdx.y * 128) * 4096;

  for (int k0 = 0; k0 < 4096; k0 += 128) {
    #pragma unroll
    for (int c2 = 0; c2 < 8; ++c2) {
      const int r  = 32 * w + 4 * c2 + sr4;
      const int gc = sc16 ^ (r & 15);
      async_copy16(Abase + (size_t)r * 4096 + k0 + gc * 8, lA + (32 * w + 4 * c2) * 128);
      async_copy16(Bbase + (size_t)r * 4096 + k0 + gc * 8, lB + (32 * w + 4 * c2) * 128);
    }
    __syncthreads();
    #pragma unroll
    for (int ks = 0; ks < 4; ++ks) {
      bf16x8 af[4], bfv[4];
      const int pc = (((ks * 4) + quad) ^ r16) * 8;   // physical chunk (ushorts)
      #pragma unroll
      for (int mi = 0; mi < 4; ++mi)
        af[mi] = *reinterpret_cast<const bf16x8*>(lA + (wr * 64 + mi * 16 + r16) * 128 + pc);
      #pragma unroll
      for (int ni = 0; ni < 4; ++ni)
        bfv[ni] = *reinterpret_cast<const bf16x8*>(lB + (wc * 64 + ni * 16 + r16) * 128 + pc);
      #pragma unroll
      for (int mi = 0; mi < 4; ++mi)
        #pragma unroll
        for (int ni = 0; ni < 4; ++ni)
          acc[mi][ni] = __builtin_amdgcn_mfma_f32_16x16x32_bf16(
              af[mi], bfv[ni], acc[mi][ni], 0, 0, 0);
    }
    __syncthreads();
  }

  const int sel = (blockIdx.y >= 8);
  const float* bias = sel ? bs : bp;
  float*  outF = sel ? outS : outP;
  ushort* outB = sel ? Sb : Pb;
  const int colbase = blockIdx.y * 128 - sel * 1024;
  #pragma unroll
  for (int mi = 0; mi < 4; ++mi) {
    #pragma unroll
    for (int ni = 0; ni < 4; ++ni) {
      const int n = colbase + wc * 64 + ni * 16 + r16;
      const float bv = bias[n];
      #pragma unroll
      for (int rg = 0; rg < 4; ++rg) {
        const int m = blockIdx.x * 128 + wr * 64 + mi * 16 + quad * 4 + rg;
        const float v = acc[mi][ni][rg] + bv;
        const size_t off = (size_t)m * 1024 + n;
        outF[off] = v;
        outB[off] = f32_to_bf16_rne(v);
      }
    }
  }
}

// ======================= head: BK=128 ======================================
// blockIdx.y==32: parent logits (A=Pb, B=Wcb). blockIdx.y==c<32: child logits
// for class c — A rows gathered via perm, B=cwb[c]; cols 0..31->child0,
// 32..95->child1. 8 K-iterations (latency-bound kernel: ~64 working blocks).
__global__ __launch_bounds__(256) void k_head(
    const ushort* __restrict__ Sb, const ushort* __restrict__ Pb,
    const ushort* __restrict__ cwb, const ushort* __restrict__ Wcb,
    const int* __restrict__ perm, const int* __restrict__ off,
    const float* __restrict__ cb0, const float* __restrict__ cb1,
    const float* __restrict__ bc,
    float* __restrict__ out0, float* __restrict__ out1,
    float* __restrict__ outParent)
{
  __shared__ __align__(16) ushort lA[128 * 128];   // 32 KB
  __shared__ __align__(16) ushort lB[128 * 128];   // 32 KB
  floatx4 acc[4][4];
  const floatx4 z4 = {0.f, 0.f, 0.f, 0.f};
  #pragma unroll
  for (int i = 0; i < 4; ++i)
    #pragma unroll
    for (int j = 0; j < 4; ++j) acc[i][j] = z4;

  const int t = threadIdx.x, w = t >> 6, lane = t & 63;
  const int wr = w >> 1, wc = w & 1, r16 = lane & 15, quad = lane >> 4;
  const int sr4 = lane >> 4, sc16 = lane & 15;

  const int isParent = (blockIdx.y == 32);
  const int c    = isParent ? 0 : blockIdx.y;
  const int off0 = isParent ? 0 : off[c];
  const int cnt  = isParent ? 4096 : (off[c + 1] - off0);
  const int m0   = blockIdx.x * 128;
  if (m0 >= cnt) return;                        // block-uniform exit

  // per-thread A-row sources (8 staging passes of 4 rows per wave)
  const ushort* Arow[8];
  #pragma unroll
  for (int c2 = 0; c2 < 8; ++c2) {
    const int r = 32 * w + 4 * c2 + sr4;
    if (isParent) Arow[c2] = Pb + (size_t)(m0 + r) * 1024;
    else          Arow[c2] = Sb + (size_t)perm[off0 + min(m0 + r, cnt - 1)] * 1024;
  }
  const ushort* Bbase = isParent ? Wcb : (cwb + (size_t)c * 128 * 1024);

  for (int k0 = 0; k0 < 1024; k0 += 128) {
    #pragma unroll
    for (int c2 = 0; c2 < 8; ++c2) {
      const int r  = 32 * w + 4 * c2 + sr4;
      const int gc = sc16 ^ (r & 15);
      async_copy16(Arow[c2] + k0 + gc * 8,                 lA + (32 * w + 4 * c2) * 128);
      async_copy16(Bbase + (size_t)r * 1024 + k0 + gc * 8, lB + (32 * w + 4 * c2) * 128);
    }
    __syncthreads();
    #pragma unroll
    for (int ks = 0; ks < 4; ++ks) {
      bf16x8 af[4], bfv[4];
      const int pc = (((ks * 4) + quad) ^ r16) * 8;
      #pragma unroll
      for (int mi = 0; mi < 4; ++mi)
        af[mi] = *reinterpret_cast<const bf16x8*>(lA + (wr * 64 + mi * 16 + r16) * 128 + pc);
      #pragma unroll
      for (int ni = 0; ni < 4; ++ni)
        bfv[ni] = *reinterpret_cast<const bf16x8*>(lB + (wc * 64 + ni * 16 + r16) * 128 + pc);
      #pragma unroll
      for (int mi = 0; mi < 4; ++mi)
        #pragma unroll
        for (int ni = 0; ni < 4; ++ni)
          acc[mi][ni] = __builtin_amdgcn_mfma_f32_16x16x32_bf16(
              af[mi], bfv[ni], acc[mi][ni], 0, 0, 0);
    }
    __syncthreads();
  }

  if (isParent) {
    if (wc == 0) {
      #pragma unroll
      for (int mi = 0; mi < 4; ++mi)
        #pragma unroll
        for (int ni = 0; ni < 2; ++ni) {
          const int n = ni * 16 + r16;          // 0..31
          const float bv = bc[n];
          #pragma unroll
          for (int rg = 0; rg < 4; ++rg) {
            const int m = m0 + wr * 64 + mi * 16 + quad * 4 + rg;
            outParent[(size_t)m * 32 + n] = acc[mi][ni][rg] + bv;
          }
        }
    }
    return;
  }

  #pragma unroll
  for (int mi = 0; mi < 4; ++mi) {
    #pragma unroll
    for (int rg = 0; rg < 4; ++rg) {
      const int gm = m0 + wr * 64 + mi * 16 + quad * 4 + rg;
      if (gm >= cnt) continue;
      const int sample = perm[off0 + gm];
      #pragma unroll
      for (int ni = 0; ni < 4; ++ni) {
        const int n = wc * 64 + ni * 16 + r16;
        if (n < 32)
          out0[(size_t)sample * 32 + n] = acc[mi][ni][rg] + cb0[c * 32 + n];
        else if (n < 96)
          out1[(size_t)sample * 64 + (n - 32)] = acc[mi][ni][rg] + cb1[c * 64 + (n - 32)];
      }
    }
  }
}

// ---------------------------------------------------------------------------

extern "C" void kernel_launch(void* const* d_in, const int* in_sizes, int n_in,
                              void* d_out, int out_size, void* d_ws, size_t ws_size,
                              hipStream_t stream) {
  const float* x   = (const float*)d_in[0];
  const int*   y   = (const int*)  d_in[1];
  const float* Wp  = (const float*)d_in[2];
  const float* bp  = (const float*)d_in[3];
  const float* Ws  = (const float*)d_in[4];
  const float* bs  = (const float*)d_in[5];
  const float* Wc  = (const float*)d_in[6];
  const float* bc  = (const float*)d_in[7];
  const float* cw0 = (const float*)d_in[8];
  const float* cb0 = (const float*)d_in[9];
  const float* cw1 = (const float*)d_in[10];
  const float* cb1 = (const float*)d_in[11];

  float* out = (float*)d_out;
  float* parent_logits = out;               // [4096,32]
  float* child0        = out + 131072;      // [4096,32]
  float* child1        = out + 262144;      // [4096,64]
  float* P             = out + 524288;      // [4096,1024]
  float* S             = out + 4718592;     // [4096,1024]

  char* ws = (char*)d_ws;
  ushort* xb   = (ushort*)(ws);                  // 32 MB   [4096][4096]
  ushort* Bt1  = (ushort*)(ws + 33554432);       // 16 MB   [2048][4096]
  ushort* Pb   = (ushort*)(ws + 50331648);       // 8 MB    [4096][1024]
  ushort* Sb   = (ushort*)(ws + 58720256);       // 8 MB    [4096][1024]
  ushort* cwb  = (ushort*)(ws + 67108864);       // 8 MB    [32][128][1024]
  ushort* Wcb  = (ushort*)(ws + 75497472);       // 256 KB  [128][1024]
  int*    perm = (int*)   (ws + 75759616);       // 16 KB
  int*    offs = (int*)   (ws + 75776000);       // 132 B

  k_prep <<<4625, 256, 0, stream>>>(x, y, Wp, Ws, Wc, cw0, cw1,
                                    xb, Bt1, cwb, Wcb, perm, offs);
  k_gemm1<<<dim3(32, 16), 256, 0, stream>>>(xb, Bt1, bp, bs, P, S, Pb, Sb);
  k_head <<<dim3(32, 33), 256, 0, stream>>>(Sb, Pb, cwb, Wcb, perm, offs,
                                            cb0, cb1, bc,
                                            child0, child1, parent_logits);
}